// Round 1
// baseline (246.850 us; speedup 1.0000x reference)
//
#include <hip/hip_runtime.h>
#include <stdint.h>

// Problem constants (fixed by the reference setup)
#define B_ 32
#define I_ 16384
#define H_ 1024
#define T_ 10
#define M_ 320   // T_*B_  (GEMM M dimension, m = t*32 + b)

typedef __attribute__((ext_vector_type(8))) short short8;  // 8 bf16 (4 VGPRs)
typedef __attribute__((ext_vector_type(4))) float f32x4;
typedef __attribute__((ext_vector_type(4))) unsigned int u32x4;

// ---------------------------------------------------------------------------
// Kernel 1: pack spikes [B][I][T] f32 -> Sbf [M=T*B][I] bf16 (exact: 0/1)
// Coalesced via LDS transpose: per block, i-chunk of 64; each b-row of the
// chunk is 640 contiguous floats.
// ---------------------------------------------------------------------------
__global__ __launch_bounds__(256) void pack_s(const float* __restrict__ spikes,
                                              uint16_t* __restrict__ Sbf) {
  __shared__ uint16_t tile[M_ * 72];  // [m][il], il<64, pad 64->72 (16B-aligned rows)
  const int i0 = blockIdx.x * 64;
  for (int u = threadIdx.x; u < 32 * 640; u += 256) {
    int b = u / 640;
    int pos = u - b * 640;          // pos = il*10 + t
    int il = pos / 10;
    int t = pos - il * 10;
    float val = spikes[(size_t)b * (I_ * T_) + (size_t)i0 * T_ + pos];
    union { float f; unsigned int u; } cv; cv.f = val;
    tile[(t * 32 + b) * 72 + il] = (uint16_t)(cv.u >> 16);  // exact for 0.0/1.0
  }
  __syncthreads();
  for (int u = threadIdx.x; u < M_ * 8; u += 256) {   // units of 8 bf16 (16B)
    int m = u >> 3;
    int il8 = u & 7;
    u32x4 w = *(const u32x4*)&tile[m * 72 + il8 * 8];
    *(u32x4*)&Sbf[(size_t)m * I_ + i0 + il8 * 8] = w;
  }
}

// ---------------------------------------------------------------------------
// Kernel 2: GEMM  partial[ks][320][1024] = Sbf * (weight*strength)
// 2-term bf16 split for fp32-class accuracy: w = hi + lo, C = S*hi + S*lo.
// Block = 256 thr (4 waves), owns full M=320 x 64 n x K-chunk, so weight and
// strength fp32 are each read exactly ONCE from HBM (conversion fused here).
// Wave w owns m in [80w, 80w+80) x all 64 n: 5x4 tiles of 16x16, 80 acc VGPRs.
// ---------------------------------------------------------------------------
__global__ __launch_bounds__(256) void gemm(const uint16_t* __restrict__ Sbf,
                                            const float* __restrict__ Wg,
                                            const float* __restrict__ Sg,
                                            float* __restrict__ partial,
                                            int kchunk) {
  // A rows padded 32->56 bf16 (112B: 16B-aligned, bank-shift 28 -> 2-way=free)
  __shared__ uint16_t A_lds[M_ * 56];
  // W packed hi|lo<<16, transposed [n][k], rows padded 32->36 words (16B-aligned)
  __shared__ unsigned int W_lds[64 * 36];

  const int nt = blockIdx.x & 15;
  const int ks = blockIdx.x >> 4;
  const int n0 = nt * 64;
  const int tid = threadIdx.x;
  const int lane = tid & 63, wid = tid >> 6;
  const int quad = lane >> 4, l15 = lane & 15;

  f32x4 acc[5][4];
#pragma unroll
  for (int a = 0; a < 5; a++)
#pragma unroll
    for (int b = 0; b < 4; b++) acc[a][b] = f32x4{0.f, 0.f, 0.f, 0.f};

  unsigned int* A32 = (unsigned int*)A_lds;
  const int stages = kchunk >> 5;       // BK = 32
  const int kofs = ks * kchunk;
  const int wn = tid & 63;              // W staging: n = lane
  const int wko = tid >> 6;             // W staging: k-octet = wave id

  for (int s = 0; s < stages; ++s) {
    const int kbase = kofs + (s << 5);
    __syncthreads();  // previous compute done reading LDS
    // ---- stage A: 320x32 bf16, 5 passes of 16B/thread ----
    {
      u32x4 av[5];
#pragma unroll
      for (int p = 0; p < 5; p++) {
        int f16 = p * 256 + tid;
        int m = f16 >> 2, kq = f16 & 3;
        av[p] = *(const u32x4*)&Sbf[(size_t)m * I_ + kbase + kq * 8];
      }
#pragma unroll
      for (int p = 0; p < 5; p++) {
        int f16 = p * 256 + tid;
        int m = f16 >> 2, kq = f16 & 3;
        *(u32x4*)&A32[m * 28 + kq * 4] = av[p];
      }
    }
    // ---- stage W: read w,s fp32 coalesced (n fast), split hi/lo, pack ----
    {
      unsigned int words[8];
#pragma unroll
      for (int p = 0; p < 8; p++) {
        int kl = 8 * wko + p;  // thread's 8 contiguous k -> 2x ds_write_b128
        size_t g = (size_t)(kbase + kl) * H_ + n0 + wn;
        float w = Wg[g] * Sg[g];
        union { float f; unsigned int u; } cv; cv.f = w;
        unsigned int hb = (cv.u + 0x7FFFu + ((cv.u >> 16) & 1u)) >> 16; // RNE bf16
        union { unsigned int u; float f; } hv; hv.u = hb << 16;
        float lo = w - hv.f;                                   // exact (Sterbenz)
        union { float f; unsigned int u; } cl; cl.f = lo;
        unsigned int lb = (cl.u + 0x7FFFu + ((cl.u >> 16) & 1u)) >> 16;
        words[p] = hb | (lb << 16);
      }
      u32x4 w0 = {words[0], words[1], words[2], words[3]};
      u32x4 w1 = {words[4], words[5], words[6], words[7]};
      *(u32x4*)&W_lds[wn * 36 + 8 * wko] = w0;
      *(u32x4*)&W_lds[wn * 36 + 8 * wko + 4] = w1;
    }
    __syncthreads();
    // ---- compute: 5 A-frags + 4 n-tiles x (hi,lo), 40 MFMA/wave/stage ----
    short8 af[5];
#pragma unroll
    for (int tm = 0; tm < 5; tm++) {
      int m = wid * 80 + tm * 16 + l15;   // A[m][k]: m=lane&15, k=quad*8+j
      af[tm] = *(const short8*)&A32[m * 28 + quad * 4];
    }
#pragma unroll
    for (int tn = 0; tn < 4; tn++) {
      int n = tn * 16 + l15;              // B[k][n]: n=lane&15, k=quad*8+j
      u32x4 r0 = *(const u32x4*)&W_lds[n * 36 + quad * 8];
      u32x4 r1 = *(const u32x4*)&W_lds[n * 36 + quad * 8 + 4];
      u32x4 hu, lu;
      hu.x = (r0.x & 0xffffu) | (r0.y << 16);
      hu.y = (r0.z & 0xffffu) | (r0.w << 16);
      hu.z = (r1.x & 0xffffu) | (r1.y << 16);
      hu.w = (r1.z & 0xffffu) | (r1.w << 16);
      lu.x = (r0.x >> 16) | (r0.y & 0xffff0000u);
      lu.y = (r0.z >> 16) | (r0.w & 0xffff0000u);
      lu.z = (r1.x >> 16) | (r1.y & 0xffff0000u);
      lu.w = (r1.z >> 16) | (r1.w & 0xffff0000u);
      short8 bhi = __builtin_bit_cast(short8, hu);
      short8 blo = __builtin_bit_cast(short8, lu);
#pragma unroll
      for (int tm = 0; tm < 5; tm++) {
        acc[tm][tn] = __builtin_amdgcn_mfma_f32_16x16x32_bf16(af[tm], bhi,
                                                              acc[tm][tn], 0, 0, 0);
        acc[tm][tn] = __builtin_amdgcn_mfma_f32_16x16x32_bf16(af[tm], blo,
                                                              acc[tm][tn], 0, 0, 0);
      }
    }
  }
  // ---- epilogue: C/D layout col=lane&15, row=quad*4+reg ----
#pragma unroll
  for (int tm = 0; tm < 5; tm++)
#pragma unroll
    for (int tn = 0; tn < 4; tn++) {
      int mrow = wid * 80 + tm * 16 + quad * 4;
      int ncol = n0 + tn * 16 + l15;
      float* dst = partial + ((size_t)ks * M_ + mrow) * H_ + ncol;
      dst[0 * H_] = acc[tm][tn].x;
      dst[1 * H_] = acc[tm][tn].y;
      dst[2 * H_] = acc[tm][tn].z;
      dst[3 * H_] = acc[tm][tn].w;
    }
}

// ---------------------------------------------------------------------------
// Kernel 3: deterministic reduction of K-split partials -> weighted [320][1024]
// ---------------------------------------------------------------------------
__global__ __launch_bounds__(256) void reduce_w(const float* __restrict__ partial,
                                                float* __restrict__ weighted,
                                                int KS) {
  int j = (blockIdx.x * 256 + threadIdx.x) * 4;
  f32x4 s = f32x4{0.f, 0.f, 0.f, 0.f};
  for (int k = 0; k < KS; k++) {
    f32x4 p = *(const f32x4*)&partial[(size_t)k * (M_ * H_) + j];
    s += p;
  }
  *(f32x4*)&weighted[j] = s;
}

// ---------------------------------------------------------------------------
// Kernel 4: LIF scan. 32 blocks x 1024 thr; block = 32 h x 32 b. Per-h columns
// are independent; batch reduction per step via LDS tree. Diag means via one
// atomicAdd per block per step (d_out diag region zeroed by hipMemsetAsync).
// ---------------------------------------------------------------------------
__global__ __launch_bounds__(1024) void scan(const float* __restrict__ weighted,
                                             const float* __restrict__ threshold,
                                             const float* __restrict__ fre0,
                                             const float* __restrict__ p_tau_mem,
                                             const float* __restrict__ p_tau_syn,
                                             const float* __restrict__ p_target,
                                             const float* __restrict__ p_lr,
                                             float* __restrict__ out) {
  __shared__ float red[32 * 33];
  __shared__ float thr_sh[32];
  const int tid = threadIdx.x;
  const int hl = tid & 31, b = tid >> 5;
  const int h = blockIdx.x * 32 + hl;
  const float alpha_mem = expf(-0.001f / p_tau_mem[0]);
  const float alpha_syn = expf(-0.001f / p_tau_syn[0]);
  const float target = p_target[0], lr = p_lr[0];
  float v = 0.f, isyn = 0.f;
  float fre = fre0[h];
  float thr = threshold[h];
  if (b == 0) thr_sh[hl] = thr;
  __syncthreads();
  for (int t = 0; t < T_; t++) {
    float w_in = weighted[(size_t)(t * 32 + b) * H_ + h];
    isyn = alpha_syn * isyn + w_in;
    v = alpha_mem * v + isyn;
    float thc = thr_sh[hl];                 // threshold BEFORE this step's update
    float spike = (v >= thc) ? 1.f : 0.f;
    v -= spike * thc;                       // reset_mode='subtract'
    out[(size_t)b * (H_ * T_) + (size_t)h * T_ + t] = spike;
    // batch-sum of spikes per h
    red[b * 33 + hl] = spike;
    __syncthreads();
    for (int s2 = 16; s2 >= 1; s2 >>= 1) {
      if (b < s2) red[b * 33 + hl] += red[(b + s2) * 33 + hl];
      __syncthreads();
    }
    float rate = (b == 0) ? red[hl] * (1.f / 32.f) : 0.f;
    __syncthreads();
    // batch-sum of post-reset v per h (for mem_means)
    red[b * 33 + hl] = v;
    __syncthreads();
    for (int s2 = 16; s2 >= 1; s2 >>= 1) {
      if (b < s2) red[b * 33 + hl] += red[(b + s2) * 33 + hl];
      __syncthreads();
    }
    if (b == 0) {                            // tid<32: all in wave 0, lanes 0..31
      fre = 0.99f * fre + 0.01f * rate;
      thr = thr + lr * (fre - target);
      thr_sh[hl] = thr;                      // for next step (sync below)
      float vs = red[hl];
      float rs = rate, ts = thr;
      for (int off = 16; off >= 1; off >>= 1) {
        vs += __shfl_down(vs, off, 32);
        rs += __shfl_down(rs, off, 32);
        ts += __shfl_down(ts, off, 32);
      }
      if (hl == 0) {
        atomicAdd(&out[327680 + t], vs * (1.f / 32768.f));  // mem mean over B,H
        atomicAdd(&out[327690 + t], rs * (1.f / 1024.f));   // rate mean over H
        atomicAdd(&out[327700 + t], ts * (1.f / 1024.f));   // thr mean over H
      }
    }
    __syncthreads();
  }
}

// ---------------------------------------------------------------------------
extern "C" void kernel_launch(void* const* d_in, const int* in_sizes, int n_in,
                              void* d_out, int out_size, void* d_ws, size_t ws_size,
                              hipStream_t stream) {
  const float* spikes    = (const float*)d_in[0];
  const float* weight    = (const float*)d_in[1];
  const float* strength  = (const float*)d_in[2];
  const float* threshold = (const float*)d_in[3];
  const float* fre0      = (const float*)d_in[4];
  const float* tau_mem   = (const float*)d_in[5];
  const float* tau_syn   = (const float*)d_in[6];
  const float* target    = (const float*)d_in[7];
  const float* lr        = (const float*)d_in[8];
  float* out = (float*)d_out;

  const size_t sbf_bytes = (size_t)M_ * I_ * 2;   // 10.5 MB bf16 A-matrix
  const size_t slice     = (size_t)M_ * H_ * 4;   // 1.31 MB per K-split partial
  int KS = 16;                                    // shrink if ws is small
  while (KS > 1 && sbf_bytes + (size_t)(KS + 1) * slice > ws_size) KS >>= 1;

  uint16_t* Sbf   = (uint16_t*)d_ws;
  float* partial  = (float*)((char*)d_ws + sbf_bytes);
  float* weighted = (float*)((char*)d_ws + sbf_bytes + (size_t)KS * slice);

  pack_s<<<I_ / 64, 256, 0, stream>>>(spikes, Sbf);
  gemm<<<16 * KS, 256, 0, stream>>>(Sbf, weight, strength, partial, I_ / KS);
  reduce_w<<<(M_ * H_) / 1024, 256, 0, stream>>>(partial, weighted, KS);
  hipMemsetAsync(out + 327680, 0, 30 * sizeof(float), stream);
  scan<<<H_ / 32, 1024, 0, stream>>>(weighted, threshold, fre0, tau_mem, tau_syn,
                                     target, lr, out);
}